// Round 5
// baseline (12785.638 us; speedup 1.0000x reference)
//
#include <hip/hip_runtime.h>
#include <cstdint>
#include <cstddef>

// ============================================================================
// PointerNet: encoder LSTM (B=512,S=256,D=2,H=256) + autoregressive pointer
// decode with jax.random.categorical (threefry2x32 partitionable, key 42).
// Output: int32 indices [512][256], trajectory-exact vs JAX reference.
//
// R5 = R4 (128 blocks x 1024 thr, 4 batches/block, weights read once/block,
// LDS gate-reduction, c in registers) + int16-quantized attention stream:
//   enc_out strictly in (-1,1) -> store q=rint(e*32768) int16 alongside fp32.
//   Main attention pass reads int16 (half the bytes of R4's dominant 17 GB
//   stream). Rigorous error bound B = 3.052e-5 * sum|h_k| + slack; if the
//   per-batch top-2 margin of (score+gumbel) <= 2B, recompute that batch in
//   fp32 (R4 path). Expected fallback ~0.5% of (b,t) -> exactness preserved.
// ws guard: if ws_size lacks room for the int16 copy, launch the pure-fp32
// R4-equivalent variant (never silently no-op).
// ============================================================================

typedef float v4f __attribute__((ext_vector_type(4)));

#define WS_ENCW4_OFF  (2u << 20)                    // [256 k][256 u][4 g] f32
#define WS_DECWI4_OFF (3u << 20)
#define WS_DECWH4_OFF (4u << 20)
#define WS_ENCK4_OFF  (5u << 20)                    // [512 b][64 k4][256 s][4] f32
#define WS_ENCK4_BYTES ((size_t)512 * 64 * 256 * 16)
#define WS_ENCQ_OFF   ((size_t)(5u << 20) + WS_ENCK4_BYTES)
#define WS_ENCQ_BYTES ((size_t)512 * 64 * 256 * 8)  // int16 copy
#define WS_NEEDED     ((size_t)(5u << 20) + WS_ENCK4_BYTES)
#define WS_NEEDED_Q   (WS_ENCQ_OFF + WS_ENCQ_BYTES)

__device__ __forceinline__ unsigned rotl32(unsigned x, int r) {
  return (x << r) | (x >> (32 - r));
}
__device__ __forceinline__ float sigm(float x) { return 1.f / (1.f + expf(-x)); }

// Threefry-2x32, 20 rounds (jax._src.prng schedule) — verified exact R1-R4.
__device__ __forceinline__ void tf2(unsigned k0, unsigned k1,
                                    unsigned& x0, unsigned& x1) {
  const unsigned k2 = k0 ^ k1 ^ 0x1BD11BDAu;
  x0 += k0; x1 += k1;
  x0 += x1; x1 = rotl32(x1, 13); x1 ^= x0;
  x0 += x1; x1 = rotl32(x1, 15); x1 ^= x0;
  x0 += x1; x1 = rotl32(x1, 26); x1 ^= x0;
  x0 += x1; x1 = rotl32(x1,  6); x1 ^= x0;
  x0 += k1; x1 += k2 + 1u;
  x0 += x1; x1 = rotl32(x1, 17); x1 ^= x0;
  x0 += x1; x1 = rotl32(x1, 29); x1 ^= x0;
  x0 += x1; x1 = rotl32(x1, 16); x1 ^= x0;
  x0 += x1; x1 = rotl32(x1, 24); x1 ^= x0;
  x0 += k2; x1 += k0 + 2u;
  x0 += x1; x1 = rotl32(x1, 13); x1 ^= x0;
  x0 += x1; x1 = rotl32(x1, 15); x1 ^= x0;
  x0 += x1; x1 = rotl32(x1, 26); x1 ^= x0;
  x0 += x1; x1 = rotl32(x1,  6); x1 ^= x0;
  x0 += k0; x1 += k1 + 3u;
  x0 += x1; x1 = rotl32(x1, 17); x1 ^= x0;
  x0 += x1; x1 = rotl32(x1, 29); x1 ^= x0;
  x0 += x1; x1 = rotl32(x1, 16); x1 ^= x0;
  x0 += x1; x1 = rotl32(x1, 24); x1 ^= x0;
  x0 += k1; x1 += k2 + 4u;
  x0 += x1; x1 = rotl32(x1, 13); x1 ^= x0;
  x0 += x1; x1 = rotl32(x1, 15); x1 ^= x0;
  x0 += x1; x1 = rotl32(x1, 26); x1 ^= x0;
  x0 += x1; x1 = rotl32(x1,  6); x1 ^= x0;
  x0 += k2; x1 += k0 + 5u;
}

// Repack W [1024 rows][256 k] row-major -> [k][u][gate] (float4 per (k,u)).
__global__ void repack_k(const float* __restrict__ eWh,
                         const float* __restrict__ dWi,
                         const float* __restrict__ dWh,
                         float* __restrict__ ws) {
  float* encW4 = (float*)((char*)ws + WS_ENCW4_OFF);
  float* decWi4 = (float*)((char*)ws + WS_DECWI4_OFF);
  float* decWh4 = (float*)((char*)ws + WS_DECWH4_OFF);
  const int n = blockIdx.x * blockDim.x + threadIdx.x;   // 65536 = 256k x 256u
  if (n >= 65536) return;
  const int k = n >> 8, u = n & 255;
#pragma unroll
  for (int g = 0; g < 4; ++g) {
    const int src = ((g << 8) + u) * 256 + k;
    const int dst = (n << 2) + g;
    encW4[dst] = eWh[src];
    decWi4[dst] = dWi[src];
    decWh4[dst] = dWh[src];
  }
}

template <bool USEQ>
__global__ void __launch_bounds__(1024)
ptrnet_kernel(const float* __restrict__ inp,    // [512][256][2]
              const float* __restrict__ eWi,    // [1024][2]
              const float* __restrict__ eBi, const float* __restrict__ eBh,
              const float* __restrict__ dBi, const float* __restrict__ dBh,
              int* __restrict__ out,            // [512][256]
              float* __restrict__ ws) {
  const int tid  = threadIdx.x;
  const int wave = tid >> 6, l = tid & 63;
  const int kq   = wave >> 2;               // K-quarter 0..3 (16 k4 each)
  const int uw   = wave & 3;                // u-slice 0..3
  const int uP   = (uw << 6) | l;           // this lane's unit in P1 (matmul)
  const int k4b  = kq << 4;
  const int bA   = tid >> 8;                // this thread's batch in P2/attn
  const int uA   = tid & 255;               // this thread's unit/score in P2/attn
  const int b0   = blockIdx.x << 2;
  const int bG   = b0 + bA;

  const v4f* encW4  = (const v4f*)((char*)ws + WS_ENCW4_OFF);
  const v4f* decWi4 = (const v4f*)((char*)ws + WS_DECWI4_OFF);
  const v4f* decWh4 = (const v4f*)((char*)ws + WS_DECWH4_OFF);
  v4f* encK4 = (v4f*)((char*)ws + WS_ENCK4_OFF);
  short4* encQ = (short4*)((char*)ws + WS_ENCQ_OFF);

  __shared__ __align__(16) float hsF[2][1024];   // h dbuf: [buf][b*256+u]
  __shared__ __align__(16) v4f dinV[256];        // dec_in [b][64 k4]
  __shared__ __align__(16) v4f red[16][256];     // partials [kq*4+b][u] (gates)
  __shared__ unsigned char maskC[4][256];
  __shared__ float partV[4][4];
  __shared__ int   partI[4][4];
  __shared__ float partV2[4][4];                 // runner-up values
  __shared__ float partBm[4][4];                 // max error bound
  __shared__ float partVf[4][4];                 // fallback pass partials
  __shared__ int   partIf[4][4];
  __shared__ int   idxS[4];

  // ---- activation-thread constants (keyed by uA) ----
  const float ebi_ = eBi[uA] + eBh[uA];
  const float ebf_ = eBi[256 + uA] + eBh[256 + uA];
  const float ebg_ = eBi[512 + uA] + eBh[512 + uA];
  const float ebo_ = eBi[768 + uA] + eBh[768 + uA];
  const float wxi0 = eWi[2 * uA], wxi1 = eWi[2 * uA + 1];
  const float wxf0 = eWi[2 * (256 + uA)], wxf1 = eWi[2 * (256 + uA) + 1];
  const float wxg0 = eWi[2 * (512 + uA)], wxg1 = eWi[2 * (512 + uA) + 1];
  const float wxo0 = eWi[2 * (768 + uA)], wxo1 = eWi[2 * (768 + uA) + 1];

  hsF[0][tid] = 0.f;
  __syncthreads();

  float c = 0.f;        // cell state for (bG, uA) — register-resident throughout
  int p = 0;

  // ---------------- encoder: 256 steps ----------------
  for (int t = 0; t < 256; ++t) {
    // P1: Wh·h partials for this (kq, u) over all 4 batches
    v4f a0 = (v4f)0.f, a1 = (v4f)0.f, a2 = (v4f)0.f, a3 = (v4f)0.f;
    const v4f* Wp = encW4 + uP;
    const v4f* hq = (const v4f*)&hsF[p][0];       // [4 b][64 k4]
#pragma unroll 2
    for (int kk = 0; kk < 16; ++kk) {
      const int k4 = k4b + kk;
      const v4f w0 = Wp[(k4 * 4 + 0) << 8];
      const v4f w1 = Wp[(k4 * 4 + 1) << 8];
      const v4f w2 = Wp[(k4 * 4 + 2) << 8];
      const v4f w3 = Wp[(k4 * 4 + 3) << 8];
      const v4f h0 = hq[k4];
      const v4f h1 = hq[64 + k4];
      const v4f h2 = hq[128 + k4];
      const v4f h3 = hq[192 + k4];
      a0 += w0 * h0.x + w1 * h0.y + w2 * h0.z + w3 * h0.w;
      a1 += w0 * h1.x + w1 * h1.y + w2 * h1.z + w3 * h1.w;
      a2 += w0 * h2.x + w1 * h2.y + w2 * h2.z + w3 * h2.w;
      a3 += w0 * h3.x + w1 * h3.y + w2 * h3.z + w3 * h3.w;
    }
    red[(kq << 2) | 0][uP] = a0;
    red[(kq << 2) | 1][uP] = a1;
    red[(kq << 2) | 2][uP] = a2;
    red[(kq << 2) | 3][uP] = a3;
    __syncthreads();                              // S_B: partials ready
    // P2: activation for (bA, uA)
    const v4f gv = red[bA][uA] + red[4 + bA][uA] + red[8 + bA][uA] + red[12 + bA][uA];
    const float2 xv = *(const float2*)(inp + (((bG) << 8) + t) * 2);
    const float ai = gv.x + ebi_ + wxi0 * xv.x + wxi1 * xv.y;
    const float af = gv.y + ebf_ + wxf0 * xv.x + wxf1 * xv.y;
    const float ag = gv.z + ebg_ + wxg0 * xv.x + wxg1 * xv.y;
    const float ao = gv.w + ebo_ + wxo0 * xv.x + wxo1 * xv.y;
    const float iv = sigm(ai), fv = sigm(af), gva = tanhf(ag), ov = sigm(ao);
    c = fv * c + iv * gva;
    const float hn = ov * tanhf(c);
    hsF[p ^ 1][(bA << 8) | uA] = hn;
    ((float*)encK4)[(((bG << 6) + (uA >> 2)) << 10) + (t << 2) + (uA & 3)] = hn;
    if (USEQ) {
      float r = rintf(hn * 32768.f);
      r = fminf(r, 32767.f);                      // |hn|<1 strictly; clamp top
      ((short*)encQ)[(((bG << 6) + (uA >> 2)) << 10) + (t << 2) + (uA & 3)] = (short)(int)r;
    }
    __syncthreads();                              // S_C: new h ready
    p ^= 1;
  }

  // ---------------- decoder: 256 steps ----------------
  const float dbi_ = dBi[uA] + dBh[uA];
  const float dbf_ = dBi[256 + uA] + dBh[256 + uA];
  const float dbg_ = dBi[512 + uA] + dBh[512 + uA];
  const float dbo_ = dBi[768 + uA] + dBh[768 + uA];
  const float NEG_INF = __int_as_float((int)0xff800000);

  if (tid < 4) idxS[tid] = -1;
  maskC[bA][uA] = 0;
  __syncthreads();

  for (int t = 0; t < 256; ++t) {
    // stage dec_in = enc_out[b, idx] (0 at t=0)
    if (tid < 256) {
      const int bb = tid >> 6, k4 = tid & 63;
      const int ix = idxS[bb];
      v4f dv = (v4f)0.f;
      if (ix >= 0) dv = encK4[((((b0 + bb) << 6) | k4) << 8) + ix];
      dinV[tid] = dv;
    }
    __syncthreads();                              // S_A: din ready

    // P1: Wh·h + Wi·din partials
    v4f a0 = (v4f)0.f, a1 = (v4f)0.f, a2 = (v4f)0.f, a3 = (v4f)0.f;
    {
      const v4f* Wh = decWh4 + uP;
      const v4f* hq = (const v4f*)&hsF[p][0];
#pragma unroll 2
      for (int kk = 0; kk < 16; ++kk) {
        const int k4 = k4b + kk;
        const v4f w0 = Wh[(k4 * 4 + 0) << 8];
        const v4f w1 = Wh[(k4 * 4 + 1) << 8];
        const v4f w2 = Wh[(k4 * 4 + 2) << 8];
        const v4f w3 = Wh[(k4 * 4 + 3) << 8];
        const v4f h0 = hq[k4];
        const v4f h1 = hq[64 + k4];
        const v4f h2 = hq[128 + k4];
        const v4f h3 = hq[192 + k4];
        a0 += w0 * h0.x + w1 * h0.y + w2 * h0.z + w3 * h0.w;
        a1 += w0 * h1.x + w1 * h1.y + w2 * h1.z + w3 * h1.w;
        a2 += w0 * h2.x + w1 * h2.y + w2 * h2.z + w3 * h2.w;
        a3 += w0 * h3.x + w1 * h3.y + w2 * h3.z + w3 * h3.w;
      }
    }
    {
      const v4f* Wi = decWi4 + uP;
#pragma unroll 2
      for (int kk = 0; kk < 16; ++kk) {
        const int k4 = k4b + kk;
        const v4f w0 = Wi[(k4 * 4 + 0) << 8];
        const v4f w1 = Wi[(k4 * 4 + 1) << 8];
        const v4f w2 = Wi[(k4 * 4 + 2) << 8];
        const v4f w3 = Wi[(k4 * 4 + 3) << 8];
        const v4f d0 = dinV[k4];
        const v4f d1 = dinV[64 + k4];
        const v4f d2 = dinV[128 + k4];
        const v4f d3 = dinV[192 + k4];
        a0 += w0 * d0.x + w1 * d0.y + w2 * d0.z + w3 * d0.w;
        a1 += w0 * d1.x + w1 * d1.y + w2 * d1.z + w3 * d1.w;
        a2 += w0 * d2.x + w1 * d2.y + w2 * d2.z + w3 * d2.w;
        a3 += w0 * d3.x + w1 * d3.y + w2 * d3.z + w3 * d3.w;
      }
    }
    red[(kq << 2) | 0][uP] = a0;
    red[(kq << 2) | 1][uP] = a1;
    red[(kq << 2) | 2][uP] = a2;
    red[(kq << 2) | 3][uP] = a3;
    __syncthreads();                              // S_B: partials ready

    // P2: activation for (bA, uA)
    const v4f gv = red[bA][uA] + red[4 + bA][uA] + red[8 + bA][uA] + red[12 + bA][uA];
    const float iv = sigm(gv.x + dbi_), fv = sigm(gv.y + dbf_);
    const float gva = tanhf(gv.z + dbg_), ov = sigm(gv.w + dbo_);
    c = fv * c + iv * gva;
    const float hn = ov * tanhf(c);
    hsF[p ^ 1][(bA << 8) | uA] = hn;
    __syncthreads();                              // S_C: new h ready
    p ^= 1;

    // ---- attention + gumbel sampling: thread (bA, s=uA) ----
    const int s = uA;
    const int masked = maskC[bA][s];
    const v4f* hq2 = ((const v4f*)&hsF[p][0]) + (bA << 6);

    // gumbel noise (threefry2x32 partitionable; exact, verified R1-R4)
    unsigned bits;
    {
      unsigned kk0 = 0u, kk1 = (unsigned)t;
      tf2(0u, 42u, kk0, kk1);
      unsigned y0 = 0u, y1 = (unsigned)((bG << 8) + s);
      tf2(kk0, kk1, y0, y1);
      bits = y0 ^ y1;
    }
    const float fr = __uint_as_float((bits >> 9) | 0x3f800000u) - 1.0f;
    const float uu = (fr > 0.f) ? fr : 1.17549435e-38f;
    const float gum = -logf(-logf(uu));

    int fi;                                       // sampled index (final)
    if (USEQ) {
      // main pass: int16 scores + rigorous bound
      float sc = 0.f, ab = 0.f;
      if (!masked) {
        const short4* Q = encQ + (((size_t)bG << 14)) + s;
#pragma unroll 8
        for (int k4 = 0; k4 < 64; ++k4) {
          const short4 qv = Q[k4 << 8];
          const v4f hv = hq2[k4];
          sc += (float)qv.x * hv.x + (float)qv.y * hv.y +
                (float)qv.z * hv.z + (float)qv.w * hv.w;
          ab += fabsf(hv.x) + fabsf(hv.y) + fabsf(hv.z) + fabsf(hv.w);
        }
        sc *= (1.f / 32768.f);
      }
      // |sc - sc_fp32| <= 2^-15 * sum|h| + accumulation slack
      const float Bl = masked ? 0.f : (ab * 3.0518e-5f + 1e-5f + 2e-6f * fabsf(sc));
      float v1 = masked ? NEG_INF : (sc + gum);
      float v2 = NEG_INF;
      int   i1 = s;
      float bm = Bl;
      // wave top-2 + bound-max reduction (first-index tie-break on v1)
#pragma unroll
      for (int off = 32; off; off >>= 1) {
        const float ov1 = __shfl_xor(v1, off, 64);
        const int   oi1 = __shfl_xor(i1, off, 64);
        const float ov2 = __shfl_xor(v2, off, 64);
        const float obm = __shfl_xor(bm, off, 64);
        const float nv2 = fmaxf(fminf(v1, ov1), fmaxf(v2, ov2));
        if (ov1 > v1 || (ov1 == v1 && oi1 < i1)) { v1 = ov1; i1 = oi1; }
        v2 = nv2;
        bm = fmaxf(bm, obm);
      }
      if (l == 0) {
        partV[bA][uw] = v1; partI[bA][uw] = i1;
        partV2[bA][uw] = v2; partBm[bA][uw] = bm;
      }
      __syncthreads();                            // S_D: partials ready
      // combine 4 wave-chunks (redundantly per thread)
      float w1 = partV[bA][0], w2 = partV2[bA][0], wb = partBm[bA][0];
      int wi = partI[bA][0];
#pragma unroll
      for (int j = 1; j < 4; ++j) {
        const float q1 = partV[bA][j], q2 = partV2[bA][j];
        const float nb = partBm[bA][j];
        const float n2 = fmaxf(fminf(w1, q1), fmaxf(w2, q2));
        if (q1 > w1) { w1 = q1; wi = partI[bA][j]; }   // strict >: lowest s wins
        w2 = n2;
        wb = fmaxf(wb, nb);
      }
      const bool fb = (w1 - w2) <= 2.f * wb;      // margin not provably safe
      // fallback: exact fp32 recompute for flagged batches
      float bvf = NEG_INF; int bif = s;
      if (fb && !masked) {
        float sf = 0.f;
        const v4f* E = encK4 + ((size_t)bG << 14) + s;
#pragma unroll 4
        for (int k4 = 0; k4 < 64; ++k4) {
          const v4f ev = E[k4 << 8];
          const v4f hv = hq2[k4];
          sf += ev.x * hv.x + ev.y * hv.y + ev.z * hv.z + ev.w * hv.w;
        }
        bvf = sf + gum;
      }
      if (fb) {
#pragma unroll
        for (int off = 32; off; off >>= 1) {
          const float ov2 = __shfl_xor(bvf, off, 64);
          const int oi2 = __shfl_xor(bif, off, 64);
          if (ov2 > bvf || (ov2 == bvf && oi2 < bif)) { bvf = ov2; bif = oi2; }
        }
        if (l == 0) { partVf[bA][uw] = bvf; partIf[bA][uw] = bif; }
      }
      __syncthreads();                            // S_G: fallback partials ready
      if (fb) {
        float v = partVf[bA][0]; int f2 = partIf[bA][0];
#pragma unroll
        for (int j = 1; j < 4; ++j) {
          const float vj = partVf[bA][j];
          if (vj > v) { v = vj; f2 = partIf[bA][j]; }
        }
        fi = f2;
      } else {
        fi = wi;
      }
    } else {
      // pure fp32 path (R4-identical)
      float sc = 0.f;
      if (!masked) {
        const v4f* E = encK4 + ((size_t)bG << 14) + s;
#pragma unroll 4
        for (int k4 = 0; k4 < 64; ++k4) {
          const v4f ev = E[k4 << 8];
          const v4f hv = hq2[k4];
          sc += ev.x * hv.x + ev.y * hv.y + ev.z * hv.z + ev.w * hv.w;
        }
      }
      float bv = masked ? NEG_INF : (sc + gum);
      int bi = s;
#pragma unroll
      for (int off = 32; off; off >>= 1) {
        const float ov2 = __shfl_xor(bv, off, 64);
        const int oi2 = __shfl_xor(bi, off, 64);
        if (ov2 > bv || (ov2 == bv && oi2 < bi)) { bv = ov2; bi = oi2; }
      }
      if (l == 0) { partV[bA][uw] = bv; partI[bA][uw] = bi; }
      __syncthreads();                            // S_D
      float v = partV[bA][0]; fi = partI[bA][0];
#pragma unroll
      for (int j = 1; j < 4; ++j) {
        const float vj = partV[bA][j];
        if (vj > v) { v = vj; fi = partI[bA][j]; }
      }
    }

    if (uA == 0) { idxS[bA] = fi; out[(bG << 8) + t] = fi; }
    if (uA == fi) maskC[bA][uA] = 1;
    __syncthreads();                              // S_E: idx/mask ready
  }
}

extern "C" void kernel_launch(void* const* d_in, const int* in_sizes, int n_in,
                              void* d_out, int out_size, void* d_ws, size_t ws_size,
                              hipStream_t stream) {
  (void)in_sizes; (void)n_in; (void)out_size;
  if (ws_size < WS_NEEDED) return;

  const float* inp = (const float*)d_in[0];
  const float* eWi = (const float*)d_in[1];
  const float* eWh = (const float*)d_in[2];
  const float* eBi = (const float*)d_in[3];
  const float* eBh = (const float*)d_in[4];
  const float* dWi = (const float*)d_in[5];
  const float* dWh = (const float*)d_in[6];
  const float* dBi = (const float*)d_in[7];
  const float* dBh = (const float*)d_in[8];
  int* out = (int*)d_out;
  float* wsf = (float*)d_ws;

  hipLaunchKernelGGL(repack_k, dim3(256), dim3(256), 0, stream, eWh, dWi, dWh, wsf);
  if (ws_size >= WS_NEEDED_Q) {
    hipLaunchKernelGGL(ptrnet_kernel<true>, dim3(128), dim3(1024), 0, stream,
                       inp, eWi, eBi, eBh, dBi, dBh, out, wsf);
  } else {
    hipLaunchKernelGGL(ptrnet_kernel<false>, dim3(128), dim3(1024), 0, stream,
                       inp, eWi, eBi, eBh, dBi, dBh, out, wsf);
  }
}

// Round 6
// 12058.256 us; speedup vs baseline: 1.0603x; 1.0603x over previous
//
#include <hip/hip_runtime.h>
#include <cstdint>
#include <cstddef>

// ============================================================================
// PointerNet: encoder LSTM (B=512,S=256,D=2,H=256) + autoregressive pointer
// decode with jax.random.categorical (threefry2x32 partitionable, key 42).
// Output: int32 indices [512][256], trajectory-exact vs JAX reference.
//
// R6 = R4 core (128 blocks x 1024 thr, 4 batches/block, weights read once per
// block, LDS gate-reduction, c register-resident) + attention restructured:
//  - R5 evidence: attention is load-INSTRUCTION/latency bound, not byte bound
//    (halving bytes left dur unchanged at half the fetch rate). So R6 halves
//    the issued wave-load count instead:
//  - enc_out stored s-major encS[b][s][k] (natural row-major). Attention
//    thread j reads 64 contiguous v4f for the j-th ACTIVE s (compacted list,
//    swap-remove; active count at step t is exactly 256-t). Waves past the
//    active count issue nothing (execz skip). Bytes/lines = R4; instrs ~1/2.
//  - int16 path removed (R5: +1 ms VALU, no benefit).
// ============================================================================

typedef float v4f __attribute__((ext_vector_type(4)));

#define WS_ENCW4_OFF  (2u << 20)                    // [256 k][256 u][4 g] f32
#define WS_DECWI4_OFF (3u << 20)
#define WS_DECWH4_OFF (4u << 20)
#define WS_ENCS_OFF   (5u << 20)                    // [512 b][256 s][256 k] f32
#define WS_NEEDED     ((size_t)(5u << 20) + (size_t)512 * 256 * 256 * 4)

__device__ __forceinline__ unsigned rotl32(unsigned x, int r) {
  return (x << r) | (x >> (32 - r));
}
__device__ __forceinline__ float sigm(float x) { return 1.f / (1.f + expf(-x)); }

// Threefry-2x32, 20 rounds (jax._src.prng schedule) — verified exact R1-R5.
__device__ __forceinline__ void tf2(unsigned k0, unsigned k1,
                                    unsigned& x0, unsigned& x1) {
  const unsigned k2 = k0 ^ k1 ^ 0x1BD11BDAu;
  x0 += k0; x1 += k1;
  x0 += x1; x1 = rotl32(x1, 13); x1 ^= x0;
  x0 += x1; x1 = rotl32(x1, 15); x1 ^= x0;
  x0 += x1; x1 = rotl32(x1, 26); x1 ^= x0;
  x0 += x1; x1 = rotl32(x1,  6); x1 ^= x0;
  x0 += k1; x1 += k2 + 1u;
  x0 += x1; x1 = rotl32(x1, 17); x1 ^= x0;
  x0 += x1; x1 = rotl32(x1, 29); x1 ^= x0;
  x0 += x1; x1 = rotl32(x1, 16); x1 ^= x0;
  x0 += x1; x1 = rotl32(x1, 24); x1 ^= x0;
  x0 += k2; x1 += k0 + 2u;
  x0 += x1; x1 = rotl32(x1, 13); x1 ^= x0;
  x0 += x1; x1 = rotl32(x1, 15); x1 ^= x0;
  x0 += x1; x1 = rotl32(x1, 26); x1 ^= x0;
  x0 += x1; x1 = rotl32(x1,  6); x1 ^= x0;
  x0 += k0; x1 += k1 + 3u;
  x0 += x1; x1 = rotl32(x1, 17); x1 ^= x0;
  x0 += x1; x1 = rotl32(x1, 29); x1 ^= x0;
  x0 += x1; x1 = rotl32(x1, 16); x1 ^= x0;
  x0 += x1; x1 = rotl32(x1, 24); x1 ^= x0;
  x0 += k1; x1 += k2 + 4u;
  x0 += x1; x1 = rotl32(x1, 13); x1 ^= x0;
  x0 += x1; x1 = rotl32(x1, 15); x1 ^= x0;
  x0 += x1; x1 = rotl32(x1, 26); x1 ^= x0;
  x0 += x1; x1 = rotl32(x1,  6); x1 ^= x0;
  x0 += k2; x1 += k0 + 5u;
}

// Repack W [1024 rows][256 k] row-major -> [k][u][gate] (float4 per (k,u)).
__global__ void repack_k(const float* __restrict__ eWh,
                         const float* __restrict__ dWi,
                         const float* __restrict__ dWh,
                         float* __restrict__ ws) {
  float* encW4 = (float*)((char*)ws + WS_ENCW4_OFF);
  float* decWi4 = (float*)((char*)ws + WS_DECWI4_OFF);
  float* decWh4 = (float*)((char*)ws + WS_DECWH4_OFF);
  const int n = blockIdx.x * blockDim.x + threadIdx.x;   // 65536 = 256k x 256u
  if (n >= 65536) return;
  const int k = n >> 8, u = n & 255;
#pragma unroll
  for (int g = 0; g < 4; ++g) {
    const int src = ((g << 8) + u) * 256 + k;
    const int dst = (n << 2) + g;
    encW4[dst] = eWh[src];
    decWi4[dst] = dWi[src];
    decWh4[dst] = dWh[src];
  }
}

__global__ void __launch_bounds__(1024)
ptrnet_kernel(const float* __restrict__ inp,    // [512][256][2]
              const float* __restrict__ eWi,    // [1024][2]
              const float* __restrict__ eBi, const float* __restrict__ eBh,
              const float* __restrict__ dBi, const float* __restrict__ dBh,
              int* __restrict__ out,            // [512][256]
              float* __restrict__ ws) {
  const int tid  = threadIdx.x;
  const int wave = tid >> 6, l = tid & 63;
  const int kq   = wave >> 2;               // K-quarter 0..3 (16 k4 each)
  const int uw   = wave & 3;                // u-slice 0..3
  const int uP   = (uw << 6) | l;           // this lane's unit in P1 (matmul)
  const int k4b  = kq << 4;
  const int bA   = tid >> 8;                // this thread's batch in P2/attn
  const int uA   = tid & 255;               // this thread's unit/slot in P2/attn
  const int b0   = blockIdx.x << 2;
  const int bG   = b0 + bA;

  const v4f* encW4  = (const v4f*)((char*)ws + WS_ENCW4_OFF);
  const v4f* decWi4 = (const v4f*)((char*)ws + WS_DECWI4_OFF);
  const v4f* decWh4 = (const v4f*)((char*)ws + WS_DECWH4_OFF);
  v4f* encS = (v4f*)((char*)ws + WS_ENCS_OFF);   // [b][s][64 k4] v4f

  __shared__ __align__(16) float hsF[2][1024];   // h dbuf: [buf][b*256+u]
  __shared__ __align__(16) v4f dinV[256];        // dec_in [b][64 k4]
  __shared__ __align__(16) v4f red[16][256];     // partials [kq*4+b][u] (gates)
  __shared__ short actS[4][256];                 // compacted active s list
  __shared__ short posS[4][256];                 // position of s in actS
  __shared__ float partV[4][4];
  __shared__ int   partI[4][4];
  __shared__ int   idxS[4];

  // ---- activation-thread constants (keyed by uA) ----
  const float ebi_ = eBi[uA] + eBh[uA];
  const float ebf_ = eBi[256 + uA] + eBh[256 + uA];
  const float ebg_ = eBi[512 + uA] + eBh[512 + uA];
  const float ebo_ = eBi[768 + uA] + eBh[768 + uA];
  const float wxi0 = eWi[2 * uA], wxi1 = eWi[2 * uA + 1];
  const float wxf0 = eWi[2 * (256 + uA)], wxf1 = eWi[2 * (256 + uA) + 1];
  const float wxg0 = eWi[2 * (512 + uA)], wxg1 = eWi[2 * (512 + uA) + 1];
  const float wxo0 = eWi[2 * (768 + uA)], wxo1 = eWi[2 * (768 + uA) + 1];

  hsF[0][tid] = 0.f;
  __syncthreads();

  float c = 0.f;        // cell state for (bG, uA) — register-resident throughout
  int p = 0;

  // ---------------- encoder: 256 steps ----------------
  for (int t = 0; t < 256; ++t) {
    // P1: Wh·h partials for this (kq, u) over all 4 batches
    v4f a0 = (v4f)0.f, a1 = (v4f)0.f, a2 = (v4f)0.f, a3 = (v4f)0.f;
    const v4f* Wp = encW4 + uP;
    const v4f* hq = (const v4f*)&hsF[p][0];       // [4 b][64 k4]
#pragma unroll 2
    for (int kk = 0; kk < 16; ++kk) {
      const int k4 = k4b + kk;
      const v4f w0 = Wp[(k4 * 4 + 0) << 8];
      const v4f w1 = Wp[(k4 * 4 + 1) << 8];
      const v4f w2 = Wp[(k4 * 4 + 2) << 8];
      const v4f w3 = Wp[(k4 * 4 + 3) << 8];
      const v4f h0 = hq[k4];
      const v4f h1 = hq[64 + k4];
      const v4f h2 = hq[128 + k4];
      const v4f h3 = hq[192 + k4];
      a0 += w0 * h0.x + w1 * h0.y + w2 * h0.z + w3 * h0.w;
      a1 += w0 * h1.x + w1 * h1.y + w2 * h1.z + w3 * h1.w;
      a2 += w0 * h2.x + w1 * h2.y + w2 * h2.z + w3 * h2.w;
      a3 += w0 * h3.x + w1 * h3.y + w2 * h3.z + w3 * h3.w;
    }
    red[(kq << 2) | 0][uP] = a0;
    red[(kq << 2) | 1][uP] = a1;
    red[(kq << 2) | 2][uP] = a2;
    red[(kq << 2) | 3][uP] = a3;
    __syncthreads();                              // S_B: partials ready
    // P2: activation for (bA, uA)
    const v4f gv = red[bA][uA] + red[4 + bA][uA] + red[8 + bA][uA] + red[12 + bA][uA];
    const float2 xv = *(const float2*)(inp + (((bG) << 8) + t) * 2);
    const float ai = gv.x + ebi_ + wxi0 * xv.x + wxi1 * xv.y;
    const float af = gv.y + ebf_ + wxf0 * xv.x + wxf1 * xv.y;
    const float ag = gv.z + ebg_ + wxg0 * xv.x + wxg1 * xv.y;
    const float ao = gv.w + ebo_ + wxo0 * xv.x + wxo1 * xv.y;
    const float iv = sigm(ai), fv = sigm(af), gva = tanhf(ag), ov = sigm(ao);
    c = fv * c + iv * gva;
    const float hn = ov * tanhf(c);
    hsF[p ^ 1][(bA << 8) | uA] = hn;
    // s-major store: encS[bG][t][uA] — 256 consecutive floats per batch
    ((float*)encS)[(((bG << 8) | t) << 8) | uA] = hn;
    __syncthreads();                              // S_C: new h ready
    p ^= 1;
  }

  // ---------------- decoder: 256 steps ----------------
  const float dbi_ = dBi[uA] + dBh[uA];
  const float dbf_ = dBi[256 + uA] + dBh[256 + uA];
  const float dbg_ = dBi[512 + uA] + dBh[512 + uA];
  const float dbo_ = dBi[768 + uA] + dBh[768 + uA];
  const float NEG_INF = __int_as_float((int)0xff800000);

  if (tid < 4) idxS[tid] = -1;
  actS[bA][uA] = (short)uA;                       // all s active initially
  posS[bA][uA] = (short)uA;
  __syncthreads();

  for (int t = 0; t < 256; ++t) {
    // stage dec_in = enc_out[b, idx] (0 at t=0) — contiguous row read
    if (tid < 256) {
      const int bb = tid >> 6, k4 = tid & 63;
      const int ix = idxS[bb];
      v4f dv = (v4f)0.f;
      if (ix >= 0) dv = encS[((((b0 + bb) << 8) | ix) << 6) + k4];
      dinV[tid] = dv;
    }
    __syncthreads();                              // S_A: din ready

    // P1: Wh·h + Wi·din partials
    v4f a0 = (v4f)0.f, a1 = (v4f)0.f, a2 = (v4f)0.f, a3 = (v4f)0.f;
    {
      const v4f* Wh = decWh4 + uP;
      const v4f* hq = (const v4f*)&hsF[p][0];
#pragma unroll 2
      for (int kk = 0; kk < 16; ++kk) {
        const int k4 = k4b + kk;
        const v4f w0 = Wh[(k4 * 4 + 0) << 8];
        const v4f w1 = Wh[(k4 * 4 + 1) << 8];
        const v4f w2 = Wh[(k4 * 4 + 2) << 8];
        const v4f w3 = Wh[(k4 * 4 + 3) << 8];
        const v4f h0 = hq[k4];
        const v4f h1 = hq[64 + k4];
        const v4f h2 = hq[128 + k4];
        const v4f h3 = hq[192 + k4];
        a0 += w0 * h0.x + w1 * h0.y + w2 * h0.z + w3 * h0.w;
        a1 += w0 * h1.x + w1 * h1.y + w2 * h1.z + w3 * h1.w;
        a2 += w0 * h2.x + w1 * h2.y + w2 * h2.z + w3 * h2.w;
        a3 += w0 * h3.x + w1 * h3.y + w2 * h3.z + w3 * h3.w;
      }
    }
    {
      const v4f* Wi = decWi4 + uP;
#pragma unroll 2
      for (int kk = 0; kk < 16; ++kk) {
        const int k4 = k4b + kk;
        const v4f w0 = Wi[(k4 * 4 + 0) << 8];
        const v4f w1 = Wi[(k4 * 4 + 1) << 8];
        const v4f w2 = Wi[(k4 * 4 + 2) << 8];
        const v4f w3 = Wi[(k4 * 4 + 3) << 8];
        const v4f d0 = dinV[k4];
        const v4f d1 = dinV[64 + k4];
        const v4f d2 = dinV[128 + k4];
        const v4f d3 = dinV[192 + k4];
        a0 += w0 * d0.x + w1 * d0.y + w2 * d0.z + w3 * d0.w;
        a1 += w0 * d1.x + w1 * d1.y + w2 * d1.z + w3 * d1.w;
        a2 += w0 * d2.x + w1 * d2.y + w2 * d2.z + w3 * d2.w;
        a3 += w0 * d3.x + w1 * d3.y + w2 * d3.z + w3 * d3.w;
      }
    }
    red[(kq << 2) | 0][uP] = a0;
    red[(kq << 2) | 1][uP] = a1;
    red[(kq << 2) | 2][uP] = a2;
    red[(kq << 2) | 3][uP] = a3;
    __syncthreads();                              // S_B: partials ready

    // P2: activation for (bA, uA)
    const v4f gv = red[bA][uA] + red[4 + bA][uA] + red[8 + bA][uA] + red[12 + bA][uA];
    const float iv = sigm(gv.x + dbi_), fv = sigm(gv.y + dbf_);
    const float gva = tanhf(gv.z + dbg_), ov = sigm(gv.w + dbo_);
    c = fv * c + iv * gva;
    const float hn = ov * tanhf(c);
    hsF[p ^ 1][(bA << 8) | uA] = hn;
    __syncthreads();                              // S_C: new h ready
    p ^= 1;

    // ---- attention over ACTIVE s only (compacted list) ----
    const int cnt = 256 - t;                      // exact active count
    float bv = NEG_INF;
    int bi = 0x7fffffff;                          // inactive: +inf index
    if (uA < cnt) {
      const int s = actS[bA][uA];
      float sc0 = 0.f, sc1 = 0.f;
      const v4f* E = encS + ((((size_t)bG << 8) | s) << 6);
      const v4f* hq2 = ((const v4f*)&hsF[p][0]) + (bA << 6);
#pragma unroll 8
      for (int k4 = 0; k4 < 64; k4 += 2) {
        const v4f e0 = E[k4], e1 = E[k4 + 1];
        const v4f h0 = hq2[k4], h1 = hq2[k4 + 1];
        sc0 += e0.x * h0.x + e0.y * h0.y + e0.z * h0.z + e0.w * h0.w;
        sc1 += e1.x * h1.x + e1.y * h1.y + e1.z * h1.z + e1.w * h1.w;
      }
      const float sc = sc0 + sc1;
      // gumbel noise (threefry2x32 partitionable; exact, verified R1-R5)
      unsigned bits;
      {
        unsigned kk0 = 0u, kk1 = (unsigned)t;
        tf2(0u, 42u, kk0, kk1);
        unsigned y0 = 0u, y1 = (unsigned)((bG << 8) + s);
        tf2(kk0, kk1, y0, y1);
        bits = y0 ^ y1;
      }
      const float fr = __uint_as_float((bits >> 9) | 0x3f800000u) - 1.0f;
      const float uu = (fr > 0.f) ? fr : 1.17549435e-38f;
      const float gum = -logf(-logf(uu));
      bv = sc + gum;
      bi = s;
    }
    // wave argmax over true s indices, lowest-s tie-break (matches jnp.argmax)
#pragma unroll
    for (int off = 32; off; off >>= 1) {
      const float ov2 = __shfl_xor(bv, off, 64);
      const int oi2 = __shfl_xor(bi, off, 64);
      if (ov2 > bv || (ov2 == bv && oi2 < bi)) { bv = ov2; bi = oi2; }
    }
    if (l == 0) { partV[bA][uw] = bv; partI[bA][uw] = bi; }
    __syncthreads();                              // S_D: wave partials ready
    // final cross-chunk argmax (redundant per thread of batch)
    float v = partV[bA][0]; int fi = partI[bA][0];
#pragma unroll
    for (int j = 1; j < 4; ++j) {
      const float vj = partV[bA][j];
      const int ij = partI[bA][j];
      if (vj > v || (vj == v && ij < fi)) { v = vj; fi = ij; }
    }
    if (uA == 0) {
      idxS[bA] = fi;
      out[(bG << 8) + t] = fi;
      // swap-remove fi from active list
      const int pf = posS[bA][fi];
      const short ls = actS[bA][cnt - 1];
      actS[bA][pf] = ls;
      posS[bA][ls] = (short)pf;
    }
    __syncthreads();                              // S_E: idx/list ready
  }
}

extern "C" void kernel_launch(void* const* d_in, const int* in_sizes, int n_in,
                              void* d_out, int out_size, void* d_ws, size_t ws_size,
                              hipStream_t stream) {
  (void)in_sizes; (void)n_in; (void)out_size;
  if (ws_size < WS_NEEDED) return;   // need ~139 MB scratch

  const float* inp = (const float*)d_in[0];
  const float* eWi = (const float*)d_in[1];
  const float* eWh = (const float*)d_in[2];
  const float* eBi = (const float*)d_in[3];
  const float* eBh = (const float*)d_in[4];
  const float* dWi = (const float*)d_in[5];
  const float* dWh = (const float*)d_in[6];
  const float* dBi = (const float*)d_in[7];
  const float* dBh = (const float*)d_in[8];
  int* out = (int*)d_out;
  float* wsf = (float*)d_ws;

  hipLaunchKernelGGL(repack_k, dim3(256), dim3(256), 0, stream, eWh, dWi, dWh, wsf);
  hipLaunchKernelGGL(ptrnet_kernel, dim3(128), dim3(1024), 0, stream,
                     inp, eWi, eBi, eBh, dBi, dBh, out, wsf);
}